// Round 3
// baseline (400.027 us; speedup 1.0000x reference)
//
#include <hip/hip_runtime.h>
#include <cstddef>
#include <cstdint>

#define NTOK 4096
#define NB_  8

// 0.25 (=1/sqrt(Cq)) * log2(e): folded into q so flash can use raw exp2.
#define QSCALE 0.36067376022224085f

typedef float f32x4  __attribute__((ext_vector_type(4)));
typedef float f32x16 __attribute__((ext_vector_type(16)));
typedef short s16x8  __attribute__((ext_vector_type(8)));

#if __has_builtin(__builtin_amdgcn_exp2f)
#define EXP2F(x) __builtin_amdgcn_exp2f(x)
#else
#define EXP2F(x) exp2f(x)
#endif

static __device__ __forceinline__ unsigned short f2bf(float f) {
    unsigned u = __float_as_uint(f);
    unsigned r = (u + 0x7FFFu + ((u >> 16) & 1u)) >> 16;
    return (unsigned short)r;
}

// 2 f32 -> packed bf16 pair (low half = a), RNE.
static __device__ __forceinline__ unsigned cvtpkbf(float a, float b) {
    unsigned r;
    asm("v_cvt_pk_bf16_f32 %0, %1, %2" : "=v"(r) : "v"(a), "v"(b));
    return r;
}

// v_permlane32_swap_b32: ret.x = [a(lanes0-31) | b(lanes0-31)],
//                        ret.y = [a(lanes32-63) | b(lanes32-63)].
static __device__ __forceinline__ uint2 plswap32(unsigned a, unsigned b) {
#if __has_builtin(__builtin_amdgcn_permlane32_swap)
    auto r = __builtin_amdgcn_permlane32_swap((int)a, (int)b, false, false);
    return make_uint2((unsigned)r[0], (unsigned)r[1]);
#else
    const int xa = (((int)threadIdx.x & 63) ^ 32) << 2;
    const unsigned pa = (unsigned)__builtin_amdgcn_ds_bpermute(xa, (int)a);
    const unsigned pb = (unsigned)__builtin_amdgcn_ds_bpermute(xa, (int)b);
    const bool hi = (threadIdx.x & 32) != 0;
    return make_uint2(hi ? pb : a, hi ? b : pa);
#endif
}

// async global(16B/lane) -> LDS(base + lane*16), wave-level
static __device__ __forceinline__ void gload16(const void* g, void* l) {
    __builtin_amdgcn_global_load_lds(
        (const __attribute__((address_space(1))) unsigned int*)g,
        (__attribute__((address_space(3))) unsigned int*)l, 16, 0, 0);
}

// ---------------- P0: weights fp32 -> bf16 ----------------
__global__ __launch_bounds__(256) void wcvt_kernel(
    const float* __restrict__ Wq, const float* __restrict__ Wk, const float* __restrict__ Wv,
    unsigned short* __restrict__ wvb, unsigned short* __restrict__ wqb,
    unsigned short* __restrict__ wkb)
{
    int i = blockIdx.x * 256 + threadIdx.x;  // 0..20479
    if (i < 16384)      wvb[i]         = f2bf(Wv[i]);
    else if (i < 18432) wqb[i - 16384] = f2bf(Wq[i - 16384]);
    else                wkb[i - 18432] = f2bf(Wk[i - 18432]);
}

// ---------------- P1: fused transpose + projections ----------------
// Flat grid 512 blocks; b = blk & 7 pins each batch to one XCD so outputs land
// in the L2 flash will read. V is written in flash's fragment-major layout:
// v3[b][jt=j>>6][s=(j>>4)&3][h=(j>>3)&1][c][e=j&7]
// MFMA operand order chosen so each thread's 4 accumulator elements map to
// CONSECUTIVE addresses -> all stores are 8B uint2, wave-coalesced.
__global__ __launch_bounds__(256) void proj_kernel(
    const float* __restrict__ x,
    const unsigned short* __restrict__ wvb, const unsigned short* __restrict__ wqb,
    const unsigned short* __restrict__ wkb,
    const float* __restrict__ bq, const float* __restrict__ bk, const float* __restrict__ bv,
    unsigned short* __restrict__ qb, unsigned short* __restrict__ kb,
    unsigned short* __restrict__ vt)
{
    __shared__ float lt[128][68];   // [c][n0..63], padded rows (16B-aligned stride)
    const int t = threadIdx.x;
    const int w = t >> 6, lane = t & 63;
    const int c16 = lane & 15, g16 = lane >> 4;
    const int b  = blockIdx.x & 7;
    const int n0 = (blockIdx.x >> 3) * 64;

    // stage x tile: 128 rows x 64 floats
    {
        const int n4 = t & 15;
#pragma unroll
        for (int pass = 0; pass < 8; ++pass) {
            const int c = (t >> 4) + 16 * pass;
            const float4 val = ((const float4*)(x + ((size_t)b * 128 + c) * NTOK + n0))[n4];
            *(float4*)&lt[c][n4 * 4] = val;
        }
    }
    __syncthreads();

    // xf fragments for this wave's 16 tokens (token = n0 + 16w + c16)
    // A-frag view: A[m=token(c16)][k=ch 8g16+e]; B-frag view: B[k=ch][n=token(c16)]
    const int nl = 16 * w + c16;
    s16x8 xf[4];
#pragma unroll
    for (int kc = 0; kc < 4; ++kc) {
        unsigned rr[8];
#pragma unroll
        for (int i = 0; i < 8; ++i) {
            const unsigned u = __float_as_uint(lt[32 * kc + 8 * g16 + i][nl]);
            rr[i] = u + 0x7FFFu + ((u >> 16) & 1u);
        }
        union { s16x8 v; unsigned u[4]; } cvt;
#pragma unroll
        for (int d = 0; d < 4; ++d)
            cvt.u[d] = __builtin_amdgcn_perm(rr[2 * d + 1], rr[2 * d], 0x07060302u);
        xf[kc] = cvt.v;
    }

    // ---- V = Wv * X  (fragment-major for flash) ----
    // mfma(xf, wf): D[m=token 4g16+r][n=c_out 16mt+c16].
    // token j = n0 + 16w + 4g16 + r: s=w, h=g16>>1, e=4(g16&1)+r -> r contiguous.
    unsigned short* vwp = vt + (size_t)b * (NTOK * 128) +
                          (size_t)(((n0 >> 6) * 8) + 2 * w + (g16 >> 1)) * 1024 + 4 * (g16 & 1);
#pragma unroll
    for (int mt = 0; mt < 8; ++mt) {
        f32x4 acc = {0.f, 0.f, 0.f, 0.f};
#pragma unroll
        for (int kc = 0; kc < 4; ++kc) {
            const s16x8 wf = *(const s16x8*)(wvb + (size_t)(16 * mt + c16) * 128 + 32 * kc + 8 * g16);
            acc = __builtin_amdgcn_mfma_f32_16x16x32_bf16(xf[kc], wf, acc, 0, 0, 0);
        }
        const float bvv = bv[16 * mt + c16];
        uint2 pkv;
        pkv.x = cvtpkbf(acc[0] + bvv, acc[1] + bvv);
        pkv.y = cvtpkbf(acc[2] + bvv, acc[3] + bvv);
        *(uint2*)(vwp + (size_t)(16 * mt + c16) * 8) = pkv;
    }
    // ---- Q, K ----
    // mfma(wqf, xf): D[m=qch 4g16+r][n=token c16] -> 4 consecutive qch per thread.
    f32x4 aq = {0.f, 0.f, 0.f, 0.f}, ak = {0.f, 0.f, 0.f, 0.f};
#pragma unroll
    for (int kc = 0; kc < 4; ++kc) {
        const s16x8 wqf = *(const s16x8*)(wqb + (size_t)c16 * 128 + 32 * kc + 8 * g16);
        const s16x8 wkf = *(const s16x8*)(wkb + (size_t)c16 * 128 + 32 * kc + 8 * g16);
        aq = __builtin_amdgcn_mfma_f32_16x16x32_bf16(wqf, xf[kc], aq, 0, 0, 0);
        ak = __builtin_amdgcn_mfma_f32_16x16x32_bf16(wkf, xf[kc], ak, 0, 0, 0);
    }
    const float4 bq4 = *(const float4*)(bq + 4 * g16);
    const float4 bk4 = *(const float4*)(bk + 4 * g16);
    const int n = n0 + 16 * w + c16;
    uint2 pq, pkk;
    pq.x  = cvtpkbf(QSCALE * (aq[0] + bq4.x), QSCALE * (aq[1] + bq4.y));
    pq.y  = cvtpkbf(QSCALE * (aq[2] + bq4.z), QSCALE * (aq[3] + bq4.w));
    pkk.x = cvtpkbf(ak[0] + bk4.x, ak[1] + bk4.y);
    pkk.y = cvtpkbf(ak[2] + bk4.z, ak[3] + bk4.w);
    *(uint2*)(qb + ((size_t)b * NTOK + n) * 16 + 4 * g16) = pq;
    *(uint2*)(kb + ((size_t)b * NTOK + n) * 16 + 4 * g16) = pkk;
}

// ---------------- P2: flash attention, LDS-shared K/V tiles ----------------
// Grid 256 blocks (= 1/CU): b = blk & 7 (XCD-pinned batch), m-tile = blk>>3 (128 q rows).
// 8 waves = (mw 0..3) x (jw 0..1): wave owns 32 q-rows (mrow = m0+32mw) and the
// jw-th 32-j half of every staged 64-j tile. V/K tiles staged via async
// global_load_lds, double-buffered; all 8 waves share each tile -> V global
// traffic /4 vs per-wave register loads. 2-way combine at the end (ct-split).
__global__ __launch_bounds__(512, 2) void flash_kernel(
    const unsigned short* __restrict__ qb, const unsigned short* __restrict__ kb,
    const unsigned short* __restrict__ vt, const float* __restrict__ x,
    const float* __restrict__ gamma, float* __restrict__ out)
{
    __shared__ __align__(16) unsigned char smem[37888];
    unsigned short* sV = (unsigned short*)smem;              // [2][8192] (16KB each)
    unsigned short* sK = (unsigned short*)(smem + 32768);    // [2][1024] (2KB each)
    float* lb = (float*)(smem + 36864);                      // [8][32]
    float* cO = (float*)smem;                                // combine alias [4][64][33]

    const int t = threadIdx.x;
    const int w = t >> 6, lane = t & 63;
    const int m31 = lane & 31, h = lane >> 5;
    const int mw = w >> 1, jw = w & 1;
    const int b  = blockIdx.x & 7;
    const int m0 = (blockIdx.x >> 3) * 128;
    const int mrow = m0 + 32 * mw;

    const unsigned short* vtile0 = vt + (size_t)b * (NTOK * 128);  // 16KB per jt tile, contiguous
    const unsigned short* ktile0 = kb + (size_t)b * (NTOK * 16);   // 2KB per jt tile, contiguous

    // Q B-frag: B[k=ch 8h+e][n=m31]; scale (incl. log2e) pre-folded into qb.
    const s16x8 qf = *(const s16x8*)(qb + ((size_t)b * NTOK + mrow + m31) * 16 + 8 * h);

    f32x16 O[4];
#pragma unroll
    for (int ct = 0; ct < 4; ++ct)
#pragma unroll
        for (int r = 0; r < 16; ++r) O[ct][r] = 0.f;
    float la0 = 0.f, la1 = 0.f, la2 = 0.f, la3 = 0.f;

    // stage tile jt_ into buffer d: V 16KB (2 calls/wave), K 2KB (waves 0,1)
#define STAGE(d, jt_) do {                                                          \
        const unsigned short* vs_ = vtile0 + (size_t)(jt_) * 8192 + w * 1024 + lane * 8; \
        gload16(vs_,       smem + (d) * 16384 + w * 2048);                          \
        gload16(vs_ + 512, smem + (d) * 16384 + w * 2048 + 1024);                   \
        if (w < 2) {                                                                \
            const unsigned short* ks_ = ktile0 + (size_t)(jt_) * 1024 + w * 512 + lane * 8; \
            gload16(ks_, smem + 32768 + (d) * 2048 + w * 1024);                     \
        }                                                                           \
    } while (0)

    STAGE(0, 0);
    __syncthreads();   // drains vmcnt -> tile 0 resident

    int cur = 0;
    for (int jt = 0; jt < 64; ++jt) {
        if (jt < 63) STAGE(cur ^ 1, jt + 1);   // async, lands before next barrier

        const unsigned short* sVc = sV + cur * 8192;
        const unsigned short* sKc = sK + cur * 1024;

        // K A-frag for this wave's 32-j half: rows j-local = 32jw + m31
        const s16x8 kf = *(const s16x8*)(sKc + (size_t)(32 * jw + m31) * 16 + 8 * h);

        // V A-frags: s-slice = 2jw + sl
        s16x8 vf[4][2];
#pragma unroll
        for (int sl = 0; sl < 2; ++sl)
#pragma unroll
            for (int ct = 0; ct < 4; ++ct)
                vf[ct][sl] = *(const s16x8*)(sVc + (2 * jw + sl) * 2048 + h * 1024 + ct * 256 + m31 * 8);

        // scores: S^T (D[j][m]) for the 32-j half
        f32x16 sd;
#pragma unroll
        for (int r = 0; r < 16; ++r) sd[r] = 0.f;
        sd = __builtin_amdgcn_mfma_f32_32x32x16_bf16(kf, qf, sd, 0, 0, 0);

        // softmax numerator: exp2 (scale folded), pack quads to bf16 pairs
        uint2 pk[4];
#pragma unroll
        for (int q = 0; q < 4; ++q) {
            const float e0 = EXP2F(sd[4 * q + 0]);
            const float e1 = EXP2F(sd[4 * q + 1]);
            const float e2 = EXP2F(sd[4 * q + 2]);
            const float e3 = EXP2F(sd[4 * q + 3]);
            la0 += e0; la1 += e1; la2 += e2; la3 += e3;
            pk[q].x = cvtpkbf(e0, e1);
            pk[q].y = cvtpkbf(e2, e3);
        }

        // register-only C->B transform via permlane32_swap (verified in r2 kernel)
        s16x8 pf[2];
#pragma unroll
        for (int s1 = 0; s1 < 2; ++s1) {
            const uint2 rx = plswap32(pk[2 * s1].x, pk[2 * s1 + 1].x);
            const uint2 ry = plswap32(pk[2 * s1].y, pk[2 * s1 + 1].y);
            union { s16x8 v; unsigned u[4]; } A;
            A.u[0] = rx.x; A.u[1] = ry.x; A.u[2] = rx.y; A.u[3] = ry.y;
            pf[s1] = A.v;
        }

        // PV: O^T[c][m] += V^T * P^T
#pragma unroll
        for (int sl = 0; sl < 2; ++sl)
#pragma unroll
            for (int ct = 0; ct < 4; ++ct)
                O[ct] = __builtin_amdgcn_mfma_f32_32x32x16_bf16(vf[ct][sl], pf[sl], O[ct], 0, 0, 0);

        __syncthreads();   // stage arrived (vmcnt drain) + all waves done with cur
        cur ^= 1;
    }
#undef STAGE

    float l_acc = (la0 + la1) + (la2 + la3);
    l_acc += __shfl_xor(l_acc, 32);   // h-halves hold disjoint j subsets

    // ---- 2-way combine between jw partners (w ^ 1): split output by ct-pair ----
    // jw=0 keeps ct{0,1} (c 0..63); jw=1 keeps ct{2,3} (c 64..127).
    if (lane < 32) lb[w * 32 + m31] = l_acc;
    if (jw == 1) {
#pragma unroll
        for (int ci = 0; ci < 2; ++ci)
#pragma unroll
            for (int r = 0; r < 16; ++r) {
                const int cl = 32 * ci + (r & 3) + 8 * (r >> 2) + 4 * h;
                cO[(mw * 64 + cl) * 33 + m31] = O[ci][r];
            }
    }
    __syncthreads();
    const float l_tot = l_acc + lb[(w ^ 1) * 32 + m31];
    if (jw == 0) {
#pragma unroll
        for (int ci = 0; ci < 2; ++ci)
#pragma unroll
            for (int r = 0; r < 16; ++r) {
                const int cl = 32 * ci + (r & 3) + 8 * (r >> 2) + 4 * h;
                O[ci][r] += cO[(mw * 64 + cl) * 33 + m31];   // read partner's A...
            }
#pragma unroll
        for (int ci = 0; ci < 2; ++ci)
#pragma unroll
            for (int r = 0; r < 16; ++r) {
                const int cl = 32 * ci + (r & 3) + 8 * (r >> 2) + 4 * h;
                cO[(mw * 64 + cl) * 33 + m31] = O[2 + ci][r]; // ...then write own B
            }
    }
    __syncthreads();
    if (jw == 1) {
#pragma unroll
        for (int ci = 0; ci < 2; ++ci)
#pragma unroll
            for (int r = 0; r < 16; ++r) {
                const int cl = 32 * ci + (r & 3) + 8 * (r >> 2) + 4 * h;
                O[2 + ci][r] += cO[(mw * 64 + cl) * 33 + m31];
            }
    }

    // ---- epilogue: each wave stores its kept 64 channels for its 32 rows ----
    const float linv = 1.f / l_tot;
    const float g = gamma[0];
#pragma unroll
    for (int ci = 0; ci < 2; ++ci) {
        const int ct = 2 * jw + ci;
#pragma unroll
        for (int r = 0; r < 16; ++r) {
            const int c = 32 * ct + (r & 3) + 8 * (r >> 2) + 4 * h;
            const size_t idx = ((size_t)b * 128 + c) * NTOK + mrow + m31;
            out[idx] = fmaf(g, O[ct][r] * linv, x[idx]);
        }
    }
}

extern "C" void kernel_launch(void* const* d_in, const int* in_sizes, int n_in,
                              void* d_out, int out_size, void* d_ws, size_t ws_size,
                              hipStream_t stream)
{
    const float* x     = (const float*)d_in[0];
    const float* Wq    = (const float*)d_in[1];
    const float* bq    = (const float*)d_in[2];
    const float* Wk    = (const float*)d_in[3];
    const float* bk    = (const float*)d_in[4];
    const float* Wv    = (const float*)d_in[5];
    const float* bv    = (const float*)d_in[6];
    const float* gamma = (const float*)d_in[7];
    float* out = (float*)d_out;

    // workspace (bf16 elements)
    unsigned short* qb  = (unsigned short*)d_ws;                 // 8*4096*16
    unsigned short* kb  = qb  + (size_t)NB_ * NTOK * 16;
    unsigned short* vt  = kb  + (size_t)NB_ * NTOK * 16;         // 8*128*4096 (fragment-major)
    unsigned short* wvb = vt  + (size_t)NB_ * 128 * NTOK;        // 128*128
    unsigned short* wqb = wvb + 16384;                           // 16*128
    unsigned short* wkb = wqb + 2048;

    wcvt_kernel<<<80, 256, 0, stream>>>(Wq, Wk, Wv, wvb, wqb, wkb);
    proj_kernel<<<512, 256, 0, stream>>>(x, wvb, wqb, wkb, bq, bk, bv, qb, kb, vt);
    flash_kernel<<<256, 512, 0, stream>>>(qb, kb, vt, x, gamma, out);
}